// Round 2
// baseline (231.754 us; speedup 1.0000x reference)
//
#include <hip/hip_runtime.h>
#include <hip/hip_bf16.h>
#include <stdint.h>

// SMHA forward: T=2048 B=2 E=1024 H=16 D=64. f32 in / f32 out, bf16 MFMA compute.
// Pipeline: gemm_qkv (f32->bf16 staged) -> transpose_v -> flash attn -> gemm_out.
// ws (bf16): Qh[B,H,T,D] @0 | Kh @8MB | Vh @16MB (reused as attn buf) | Vt[B,H,D,T] @24MB

#define T_SEQ 2048
#define BATCH 2
#define EMB   1024
#define NH    16
#define HD    64

typedef short s16;
typedef s16   bf16x8 __attribute__((ext_vector_type(8)));
typedef float f32x4  __attribute__((ext_vector_type(4)));

__device__ __forceinline__ f32x4 mfma16(bf16x8 a, bf16x8 b, f32x4 c) {
  return __builtin_amdgcn_mfma_f32_16x16x32_bf16(a, b, c, 0, 0, 0);
}

__device__ __forceinline__ void gload16(const void* g, void* l) {
  __builtin_amdgcn_global_load_lds(
      (const __attribute__((address_space(1))) uint32_t*)g,
      (__attribute__((address_space(3))) uint32_t*)l, 16, 0, 0);
}

__device__ __forceinline__ s16 f2b(float x) {
  return (s16)__builtin_bit_cast(unsigned short, __float2bfloat16(x));
}

// load 8 consecutive f32, convert to bf16x8
__device__ __forceinline__ bf16x8 cvt8(const float* p) {
  f32x4 a = *(const f32x4*)p;
  f32x4 b = *(const f32x4*)(p + 4);
  bf16x8 r;
  r[0] = f2b(a[0]); r[1] = f2b(a[1]); r[2] = f2b(a[2]); r[3] = f2b(a[3]);
  r[4] = f2b(b[0]); r[5] = f2b(b[1]); r[6] = f2b(b[2]); r[7] = f2b(b[3]);
  return r;
}

// ---------------- QKV projection GEMM (f32 inputs) ----------------
// Y = X @ W^T + b. blockIdx.y: 0..23 -> which = y>>3 (0=Q,1=K,2=V), n0=(y&7)*128.
// Output [B,H,T,D] bf16; Q pre-scaled by D^-0.5.
__global__ __launch_bounds__(256)
void gemm_qkv_kernel(const float* __restrict__ X,
                     const float* __restrict__ Wq, const float* __restrict__ bq,
                     const float* __restrict__ Wk, const float* __restrict__ bk,
                     const float* __restrict__ Wv, const float* __restrict__ bv,
                     __hip_bfloat16* __restrict__ Qh, __hip_bfloat16* __restrict__ Kh,
                     __hip_bfloat16* __restrict__ Vh)
{
  __shared__ __align__(16) s16 lA[128 * 32];
  __shared__ __align__(16) s16 lB[128 * 32];
  const int tid  = threadIdx.x;
  const int lane = tid & 63;
  const int wave = tid >> 6;
  const int which = blockIdx.y >> 3;
  const float* W = (which == 0) ? Wq : (which == 1) ? Wk : Wv;
  const float* bias = (which == 0) ? bq : (which == 1) ? bk : bv;
  __hip_bfloat16* Y = (which == 0) ? Qh : (which == 1) ? Kh : Vh;
  const int m0 = blockIdx.x * 128;
  const int n0 = (blockIdx.y & 7) * 128;
  const int srow = tid >> 2;           // 0..63
  const int scol = (tid & 3) * 8;      // 0,8,16,24
  const int wr = (wave >> 1) * 64;
  const int wc = (wave & 1) * 64;
  const int fr = lane & 15;
  const int fk = (lane >> 4) * 8;

  f32x4 acc[4][4] = {};

  for (int k0 = 0; k0 < EMB; k0 += 32) {
    bf16x8 a0 = cvt8(X + (size_t)(m0 + srow) * EMB + k0 + scol);
    bf16x8 a1 = cvt8(X + (size_t)(m0 + 64 + srow) * EMB + k0 + scol);
    bf16x8 b0 = cvt8(W + (size_t)(n0 + srow) * EMB + k0 + scol);
    bf16x8 b1 = cvt8(W + (size_t)(n0 + 64 + srow) * EMB + k0 + scol);
    *(bf16x8*)&lA[srow * 32 + scol] = a0;
    *(bf16x8*)&lA[(64 + srow) * 32 + scol] = a1;
    *(bf16x8*)&lB[srow * 32 + scol] = b0;
    *(bf16x8*)&lB[(64 + srow) * 32 + scol] = b1;
    __syncthreads();
    bf16x8 af[4], bfr[4];
#pragma unroll
    for (int i = 0; i < 4; ++i) af[i]  = *(const bf16x8*)&lA[(wr + i * 16 + fr) * 32 + fk];
#pragma unroll
    for (int i = 0; i < 4; ++i) bfr[i] = *(const bf16x8*)&lB[(wc + i * 16 + fr) * 32 + fk];
#pragma unroll
    for (int mi = 0; mi < 4; ++mi)
#pragma unroll
      for (int ni = 0; ni < 4; ++ni)
        acc[mi][ni] = mfma16(af[mi], bfr[ni], acc[mi][ni]);
    __syncthreads();
  }

  const float scale = (which == 0) ? 0.125f : 1.0f;  // D^-0.5 = 1/8
  const int fq = lane >> 4;
#pragma unroll
  for (int mi = 0; mi < 4; ++mi) {
#pragma unroll
    for (int ni = 0; ni < 4; ++ni) {
      const int nn = n0 + wc + ni * 16 + fr;
      const float bb = bias[nn];
      const int h = nn >> 6, d = nn & 63;
#pragma unroll
      for (int r = 0; r < 4; ++r) {
        const int m = m0 + wr + mi * 16 + fq * 4 + r;
        const int t = m >> 1, b = m & 1;   // row m = t*B + b
        float y = (acc[mi][ni][r] + bb) * scale;
        Y[(((size_t)b * NH + h) * T_SEQ + t) * HD + d] = __float2bfloat16(y);
      }
    }
  }
}

// ---------------- output projection GEMM: bf16 A, f32 W, f32 out ----------------
__global__ __launch_bounds__(256)
void gemm_out_kernel(const s16* __restrict__ X,    // attn [4096][1024] bf16
                     const float* __restrict__ W,  // Wo f32
                     const float* __restrict__ bias,
                     float* __restrict__ Y)        // [T,B,E] f32
{
  __shared__ __align__(16) s16 lA[128 * 32];
  __shared__ __align__(16) s16 lB[128 * 32];
  const int tid  = threadIdx.x;
  const int lane = tid & 63;
  const int wave = tid >> 6;
  const int m0 = blockIdx.x * 128;
  const int n0 = blockIdx.y * 128;
  const int srow = tid >> 2;
  const int scol = (tid & 3) * 8;
  const int wr = (wave >> 1) * 64;
  const int wc = (wave & 1) * 64;
  const int fr = lane & 15;
  const int fk = (lane >> 4) * 8;

  f32x4 acc[4][4] = {};

  for (int k0 = 0; k0 < EMB; k0 += 32) {
    // A (bf16): async global->LDS
    gload16(X + (size_t)(m0 + srow) * EMB + k0 + scol,      &lA[srow * 32 + scol]);
    gload16(X + (size_t)(m0 + 64 + srow) * EMB + k0 + scol, &lA[(64 + srow) * 32 + scol]);
    // B (f32): reg-stage + convert
    bf16x8 b0 = cvt8(W + (size_t)(n0 + srow) * EMB + k0 + scol);
    bf16x8 b1 = cvt8(W + (size_t)(n0 + 64 + srow) * EMB + k0 + scol);
    *(bf16x8*)&lB[srow * 32 + scol] = b0;
    *(bf16x8*)&lB[(64 + srow) * 32 + scol] = b1;
    __syncthreads();
    bf16x8 af[4], bfr[4];
#pragma unroll
    for (int i = 0; i < 4; ++i) af[i]  = *(const bf16x8*)&lA[(wr + i * 16 + fr) * 32 + fk];
#pragma unroll
    for (int i = 0; i < 4; ++i) bfr[i] = *(const bf16x8*)&lB[(wc + i * 16 + fr) * 32 + fk];
#pragma unroll
    for (int mi = 0; mi < 4; ++mi)
#pragma unroll
      for (int ni = 0; ni < 4; ++ni)
        acc[mi][ni] = mfma16(af[mi], bfr[ni], acc[mi][ni]);
    __syncthreads();
  }

  const int fq = lane >> 4;
#pragma unroll
  for (int mi = 0; mi < 4; ++mi) {
#pragma unroll
    for (int ni = 0; ni < 4; ++ni) {
      const int nn = n0 + wc + ni * 16 + fr;
      const float bb = bias[nn];
#pragma unroll
      for (int r = 0; r < 4; ++r) {
        const int m = m0 + wr + mi * 16 + fq * 4 + r;
        Y[(size_t)m * EMB + nn] = acc[mi][ni][r] + bb;
      }
    }
  }
}

// ---------------- V transpose: [B,H,T,D] -> [B,H,D,T] (bf16) ----------------
__global__ __launch_bounds__(256)
void transpose_v_kernel(const s16* __restrict__ Vh, s16* __restrict__ Vt)
{
  __shared__ s16 tile[64][65];
  const int bh = blockIdx.y;
  const int s0 = blockIdx.x * 64;
  const int tid = threadIdx.x;
  const int r = tid >> 3;          // 0..31
  const int c = (tid & 7) * 8;
  const s16* src = Vh + (size_t)bh * T_SEQ * HD + (size_t)s0 * HD;
#pragma unroll
  for (int half = 0; half < 2; ++half) {
    const int row = r + half * 32;
    bf16x8 v = *(const bf16x8*)&src[(size_t)row * HD + c];
#pragma unroll
    for (int j = 0; j < 8; ++j) tile[row][c + j] = v[j];
  }
  __syncthreads();
  s16* dst = Vt + (size_t)bh * HD * T_SEQ;
#pragma unroll
  for (int half = 0; half < 2; ++half) {
    const int d = r + half * 32;
    bf16x8 v;
#pragma unroll
    for (int j = 0; j < 8; ++j) v[j] = tile[c + j][d];
    *(bf16x8*)&dst[(size_t)d * T_SEQ + s0 + c] = v;
  }
}

// ---------------- flash attention (bf16 in, bf16 out) ----------------
// grid (T/64, B*H). 4 waves/block, each wave owns 16 q-rows, key tiles of 64.
__global__ __launch_bounds__(256)
void attn_kernel(const s16* __restrict__ Qh,   // [B,H,T,D]
                 const s16* __restrict__ Kh,   // [B,H,T,D]
                 const s16* __restrict__ Vt,   // [B,H,D,T]
                 __hip_bfloat16* __restrict__ attn) // rows (t*B+b)*E + h*64 + d
{
  __shared__ __align__(16) s16 lK[64 * 64];
  __shared__ __align__(16) s16 lV[64 * 64];       // Vt tile [d][s]
  __shared__ __align__(16) s16 lP[4][16 * 64];    // per-wave P
  const int tid  = threadIdx.x;
  const int lane = tid & 63;
  const int wave = tid >> 6;
  const int bh = blockIdx.y;
  const int q0 = blockIdx.x * 64 + wave * 16;
  const size_t baseK = (size_t)bh * T_SEQ * HD;
  const size_t baseV = (size_t)bh * HD * T_SEQ;
  const int fr = lane & 15;
  const int fk = (lane >> 4) * 8;
  const int fq = lane >> 4;

  bf16x8 qf0 = *(const bf16x8*)&Qh[baseK + (size_t)(q0 + fr) * HD + fk];
  bf16x8 qf1 = *(const bf16x8*)&Qh[baseK + (size_t)(q0 + fr) * HD + 32 + fk];

  float m_run[4], l_run[4];
  f32x4 o_acc[4] = {};
#pragma unroll
  for (int r = 0; r < 4; ++r) { m_run[r] = -INFINITY; l_run[r] = 0.f; }

  const int srow = tid >> 3;         // 0..31
  const int scol = (tid & 7) * 8;

  for (int s0 = 0; s0 < T_SEQ; s0 += 64) {
    gload16(Kh + baseK + (size_t)(s0 + srow) * HD + scol,      &lK[srow * 64 + scol]);
    gload16(Kh + baseK + (size_t)(s0 + 32 + srow) * HD + scol, &lK[(32 + srow) * 64 + scol]);
    gload16(Vt + baseV + (size_t)srow * T_SEQ + s0 + scol,        &lV[srow * 64 + scol]);
    gload16(Vt + baseV + (size_t)(32 + srow) * T_SEQ + s0 + scol, &lV[(32 + srow) * 64 + scol]);
    __syncthreads();

    // S = Q K^T, 4 key sub-tiles of 16
    f32x4 s_acc[4];
#pragma unroll
    for (int sc = 0; sc < 4; ++sc) {
      bf16x8 kf0 = *(const bf16x8*)&lK[(sc * 16 + fr) * 64 + fk];
      bf16x8 kf1 = *(const bf16x8*)&lK[(sc * 16 + fr) * 64 + 32 + fk];
      f32x4 z = {};
      z = mfma16(qf0, kf0, z);
      z = mfma16(qf1, kf1, z);
      s_acc[sc] = z;
    }

    // online softmax: row q = fq*4 + r, 16 lanes per row group
#pragma unroll
    for (int r = 0; r < 4; ++r) {
      float v = fmaxf(fmaxf(s_acc[0][r], s_acc[1][r]), fmaxf(s_acc[2][r], s_acc[3][r]));
      v = fmaxf(v, __shfl_xor(v, 1));
      v = fmaxf(v, __shfl_xor(v, 2));
      v = fmaxf(v, __shfl_xor(v, 4));
      v = fmaxf(v, __shfl_xor(v, 8));
      const float mn = fmaxf(m_run[r], v);
      const float sc_f = __expf(m_run[r] - mn);   // 0 when m_run=-inf
      m_run[r] = mn;
      l_run[r] *= sc_f;
#pragma unroll
      for (int dn = 0; dn < 4; ++dn) o_acc[dn][r] *= sc_f;
    }
    float rsum[4] = {0.f, 0.f, 0.f, 0.f};
#pragma unroll
    for (int sc = 0; sc < 4; ++sc)
#pragma unroll
      for (int r = 0; r < 4; ++r) {
        const float p = __expf(s_acc[sc][r] - m_run[r]);
        s_acc[sc][r] = p;
        rsum[r] += p;
      }
#pragma unroll
    for (int r = 0; r < 4; ++r) {
      float v = rsum[r];
      v += __shfl_xor(v, 1); v += __shfl_xor(v, 2);
      v += __shfl_xor(v, 4); v += __shfl_xor(v, 8);
      l_run[r] += v;
    }

    // P -> LDS (bf16), then read as A-fragments
#pragma unroll
    for (int sc = 0; sc < 4; ++sc)
#pragma unroll
      for (int r = 0; r < 4; ++r)
        lP[wave][(fq * 4 + r) * 64 + sc * 16 + fr] = f2b(s_acc[sc][r]);
    asm volatile("s_waitcnt lgkmcnt(0)" ::: "memory");

#pragma unroll
    for (int h = 0; h < 2; ++h) {
      bf16x8 pf = *(const bf16x8*)&lP[wave][fr * 64 + h * 32 + fk];
#pragma unroll
      for (int dn = 0; dn < 4; ++dn) {
        bf16x8 vf = *(const bf16x8*)&lV[(dn * 16 + fr) * 64 + h * 32 + fk];
        o_acc[dn] = mfma16(pf, vf, o_acc[dn]);
      }
    }
    __syncthreads();
  }

  const int b = bh >> 4, h = bh & 15;
#pragma unroll
  for (int r = 0; r < 4; ++r) {
    const int t = q0 + fq * 4 + r;
    const float inv = 1.0f / l_run[r];
#pragma unroll
    for (int dn = 0; dn < 4; ++dn) {
      const int d = dn * 16 + fr;
      attn[((size_t)t * BATCH + b) * EMB + h * HD + d] =
          __float2bfloat16(o_acc[dn][r] * inv);
    }
  }
}

extern "C" void kernel_launch(void* const* d_in, const int* in_sizes, int n_in,
                              void* d_out, int out_size, void* d_ws, size_t ws_size,
                              hipStream_t stream) {
  const float* query = (const float*)d_in[0];
  const float* Wq = (const float*)d_in[1];
  const float* bq = (const float*)d_in[2];
  const float* Wk = (const float*)d_in[3];
  const float* bk = (const float*)d_in[4];
  const float* Wv = (const float*)d_in[5];
  const float* bv = (const float*)d_in[6];
  const float* Wo = (const float*)d_in[7];
  const float* bo = (const float*)d_in[8];

  char* ws = (char*)d_ws;
  const size_t SZ = (size_t)BATCH * NH * T_SEQ * HD * sizeof(s16);  // 8 MB
  __hip_bfloat16* Qh = (__hip_bfloat16*)(ws);
  __hip_bfloat16* Kh = (__hip_bfloat16*)(ws + SZ);
  __hip_bfloat16* Vh = (__hip_bfloat16*)(ws + 2 * SZ);
  s16* Vt = (s16*)(ws + 3 * SZ);
  __hip_bfloat16* attnb = (__hip_bfloat16*)(ws + 2 * SZ);  // reuse Vh after transpose

  dim3 blk(256);
  gemm_qkv_kernel<<<dim3(32, 24), blk, 0, stream>>>(query, Wq, bq, Wk, bk, Wv, bv, Qh, Kh, Vh);
  transpose_v_kernel<<<dim3(32, 32), blk, 0, stream>>>((const s16*)Vh, Vt);
  attn_kernel<<<dim3(32, 32), blk, 0, stream>>>((const s16*)Qh, (const s16*)Kh, Vt, attnb);
  gemm_out_kernel<<<dim3(32, 8), blk, 0, stream>>>((const s16*)attnb, Wo, bo, (float*)d_out);
}